// Round 3
// baseline (61.143 us; speedup 1.0000x reference)
//
#include <hip/hip_runtime.h>
#include <hip/hip_cooperative_groups.h>

namespace cg = cooperative_groups;

#define NEXP 16
#define FIN 256
#define FOUT 256
#define NB 16
#define NPG 128
#define NTOT (NB * NPG)
#define MAT4 (FIN * FOUT / 4)   // 16384 float4 per (IN,OUT) matrix

// ---------------------------------------------------------------------------
// Fused cooperative kernel. grid = 256 blocks x 1024 threads (16 waves = 1
// block/CU; LDS 137 KB; __launch_bounds__(1024,4) caps VGPR at 128).
//
// Phase 1 (mix): threads tid<256 of block bid cover position pt = bid*256+tid:
//   p = pt & 16383 (float4 position), gq = pt>>14 (graph quarter).
//   Reads the 16 expert float4s once, writes 4 graphs' mixed values.
//   kern traffic: 16 MB (L3-resident).
//
// grid.sync()
//
// Phase 2 (GEMM): work id XCD-swizzled (wbid) so the 16 blocks sharing one
//   graph's 256 KB mixed matrix sit on ONE XCD -> L2-resident after first
//   fetch. Tile = 8 nodes x 256 cols; 16-way split-K (wave q owns i in
//   [16q,16q+16) for all 8 rows) -> matrix read exactly once per block.
//   Cross-wave reduction through 128 KB LDS, bias added there.
// ---------------------------------------------------------------------------
__global__ __launch_bounds__(1024, 4) void mole_fused_kernel(
    const float* __restrict__ inp,     // (N, IN)
    const int* __restrict__ n_node,    // (B,)
    const float* __restrict__ coeffs,  // (B, E)
    const float* __restrict__ kern,    // (E, IN, OUT)
    const float* __restrict__ bias,    // (OUT,)
    float* __restrict__ out,           // (N, OUT)
    float* __restrict__ mixed)         // (B, IN, OUT) scratch in d_ws
{
    __shared__ float in_s[8][FIN];        // 8 KB input rows
    __shared__ float4 red_s[16][8][64];   // 128 KB cross-wave partials
    __shared__ float cs[NB * NEXP];       // 1 KB coeffs
    __shared__ int gm[8];                 // graph id per local node

    const int tid = threadIdx.x;
    const int bid = blockIdx.x;

    // XCD-chunked swizzle: blocks bid with bid%8==x (-> XCD x) get work ids
    // [32x, 32x+32) = graphs {2x, 2x+1}; each graph's matrix stays in one L2.
    const int wbid = (bid >> 3) + ((bid & 7) << 5);
    const int n0 = wbid * 8;  // first node of this block's tile

    // ---- staging (cs, gm, in_s) ----
    if (tid < NB * NEXP) cs[tid] = coeffs[tid];
    if (tid < 8) {
        const int n = n0 + tid;
        int g = 0, acc = 0;
        for (int b = 0; b < NB; ++b) {
            acc += n_node[b];
            if (n >= acc) ++g;
        }
        gm[tid] = g;
    }
    if (tid < 512) {
        const float4* ip4 = reinterpret_cast<const float4*>(inp + (size_t)n0 * FIN);
        reinterpret_cast<float4*>(&in_s[0][0])[tid] = ip4[tid];
    }
    __syncthreads();

    // ---- phase 1: mix (tid < 256 only; 4 waves/block active) ----
    const float4* k4 = reinterpret_cast<const float4*>(kern);
    float4* m4 = reinterpret_cast<float4*>(mixed);
    if (tid < 256) {
        const int pt = bid * 256 + tid;
        const int p = pt & (MAT4 - 1);
        const int gq = pt >> 14;  // 0..3

        float4 k[NEXP];
#pragma unroll
        for (int e = 0; e < NEXP; ++e) k[e] = k4[e * MAT4 + p];

#pragma unroll
        for (int bb = 0; bb < 4; ++bb) {
            const int b = 4 * gq + bb;
            float4 acc = make_float4(0.f, 0.f, 0.f, 0.f);
#pragma unroll
            for (int e = 0; e < NEXP; ++e) {
                const float c = cs[b * NEXP + e];
                acc.x += c * k[e].x;
                acc.y += c * k[e].y;
                acc.z += c * k[e].z;
                acc.w += c * k[e].w;
            }
            m4[(size_t)b * MAT4 + p] = acc;
        }
    }

    cg::this_grid().sync();

    // ---- phase 2: GEMM ----
    const int o4 = tid & 63;   // float4 column
    const int q = tid >> 6;    // wave id = K-split group, 0..15
    const int i0 = q * 16;

    float4 acc[8];
#pragma unroll
    for (int r = 0; r < 8; ++r) acc[r] = make_float4(0.f, 0.f, 0.f, 0.f);

    const float4* m4c = reinterpret_cast<const float4*>(mixed);
    if (gm[0] == gm[7]) {  // graph-uniform tile (gm monotone)
        const float4* mb = m4c + (size_t)gm[0] * MAT4 + o4;
#pragma unroll 8
        for (int ii = 0; ii < 16; ++ii) {
            const int i = i0 + ii;
            const float4 mv = mb[(size_t)i * (FOUT / 4)];
#pragma unroll
            for (int r = 0; r < 8; ++r) {
                const float av = in_s[r][i];  // wave-uniform -> broadcast
                acc[r].x += av * mv.x;
                acc[r].y += av * mv.y;
                acc[r].z += av * mv.z;
                acc[r].w += av * mv.w;
            }
        }
    } else {
        // ragged fallback: per-node matrix stream
        for (int ii = 0; ii < 16; ++ii) {
            const int i = i0 + ii;
#pragma unroll
            for (int r = 0; r < 8; ++r) {
                const float av = in_s[r][i];
                const float4 mv = m4c[(size_t)gm[r] * MAT4 + (size_t)i * (FOUT / 4) + o4];
                acc[r].x += av * mv.x;
                acc[r].y += av * mv.y;
                acc[r].z += av * mv.z;
                acc[r].w += av * mv.w;
            }
        }
    }

    // cross-wave reduction
#pragma unroll
    for (int r = 0; r < 8; ++r) red_s[q][r][o4] = acc[r];
    __syncthreads();

    if (tid < 512) {
        const int r = tid >> 6;
        const int oc = tid & 63;
        const float4 bv = reinterpret_cast<const float4*>(bias)[oc];
        float4 t = make_float4(bv.x, bv.y, bv.z, bv.w);
#pragma unroll
        for (int qq = 0; qq < 16; ++qq) {
            const float4 v = red_s[qq][r][oc];
            t.x += v.x;
            t.y += v.y;
            t.z += v.z;
            t.w += v.w;
        }
        reinterpret_cast<float4*>(out)[(size_t)(n0 + r) * (FOUT / 4) + oc] = t;
    }
}

// ---------------------------------------------------------------------------
extern "C" void kernel_launch(void* const* d_in, const int* in_sizes, int n_in,
                              void* d_out, int out_size, void* d_ws, size_t ws_size,
                              hipStream_t stream) {
    const float* inputs = (const float*)d_in[0];   // (N, IN) f32
    const int* n_node = (const int*)d_in[1];       // (B,) i32
    const float* coeffs = (const float*)d_in[2];   // (B, E) f32
    const float* kern = (const float*)d_in[3];     // (E, IN, OUT) f32
    const float* bias = (const float*)d_in[4];     // (OUT,) f32
    float* outp = (float*)d_out;                   // (N, OUT) f32
    float* mixed = (float*)d_ws;                   // (B, IN, OUT) f32 scratch

    void* args[] = {(void*)&inputs, (void*)&n_node, (void*)&coeffs,
                    (void*)&kern, (void*)&bias, (void*)&outp, (void*)&mixed};
    hipLaunchCooperativeKernel((const void*)mole_fused_kernel,
                               dim3(256), dim3(1024), args, 0, stream);
}

// Round 4
// 21.034 us; speedup vs baseline: 2.9069x; 2.9069x over previous
//
#include <hip/hip_runtime.h>

#define NEXP 16
#define FIN 256
#define FOUT 256
#define NB 16
#define NTOT 2048
#define WCOL 16                 // output columns per block slice
#define NSLICE (FOUT / WCOL)    // 16 column slices per graph

// ---------------------------------------------------------------------------
// Single fused kernel, no cross-block deps. 256 blocks x 256 threads.
// Block = (graph g, column slice cs of 16 cols):
//   Phase A: mix m_s[i][c] = sum_e coeffs[g][e] * kern[e][i][co+c] (16 KB LDS)
//            -> each (graph, column) mixed exactly once grid-wide.
//   Phase B: stage this graph's input rows into padded LDS (133 KB).
//   Phase C: GEMM out[rows][co..co+16) from LDS only; thread = 2 rows x 1 f4col.
// XCD swizzle: the 16 blocks sharing a kern column-slice land on one XCD.
// ---------------------------------------------------------------------------
__global__ __launch_bounds__(256) void mole_onepass_kernel(
    const float* __restrict__ inp,     // (N, IN)
    const int* __restrict__ n_node,    // (B,)
    const float* __restrict__ coeffs,  // (B, E)
    const float* __restrict__ kern,    // (E, IN, OUT)
    const float* __restrict__ bias,    // (OUT,)
    float* __restrict__ out)           // (N, OUT)
{
    __shared__ float in_s[128][FIN + 4];   // pad +4 floats: 2-way banks (free)
    __shared__ float4 m_s4[FIN * (WCOL / 4)];  // [i][c4] flat, 16 KB
    __shared__ float cs_s[NEXP];

    const int tid = threadIdx.x;
    const int bid = blockIdx.x;

    // XCD-chunked decode: xcd = bid&7 owns column slices {2*xcd, 2*xcd+1}
    const int xcd = bid & 7;
    const int j = bid >> 3;               // 0..31
    const int cs = 2 * xcd + (j & 1);     // column slice 0..15
    const int g = j >> 1;                 // graph 0..15
    const int co4 = cs * (WCOL / 4);      // float4 column offset

    // graph row range via prefix scan (ragged-safe, block-uniform)
    int start = 0;
    for (int b = 0; b < NB; ++b) {
        const int nb = n_node[b];
        if (b < g) start += nb;
    }
    const int cnt = n_node[g];

    if (tid < NEXP) cs_s[tid] = coeffs[g * NEXP + tid];
    __syncthreads();

    // ---- Phase A: mix the (256 x 16) slice into m_s4 ----
    // w = tid + 256k -> i = w>>2, c4 = w&3; writes are lane-consecutive.
    const float4* k4 = reinterpret_cast<const float4*>(kern);
#pragma unroll
    for (int k = 0; k < 4; ++k) {
        const int w = tid + 256 * k;
        const int i = w >> 2;
        const int c4 = w & 3;
        const float4* kp = k4 + (size_t)i * (FOUT / 4) + co4 + c4;
        float4 acc = make_float4(0.f, 0.f, 0.f, 0.f);
#pragma unroll
        for (int e = 0; e < NEXP; ++e) {
            const float4 kv = kp[(size_t)e * (FIN * FOUT / 4)];
            const float c = cs_s[e];
            acc.x += c * kv.x;
            acc.y += c * kv.y;
            acc.z += c * kv.z;
            acc.w += c * kv.w;
        }
        m_s4[w] = acc;
    }

    const float4* ip4 = reinterpret_cast<const float4*>(inp);
    float4* out4 = reinterpret_cast<float4*>(out);
    const float4 bv = reinterpret_cast<const float4*>(bias)[co4 + (tid & 3)];

    // ---- row chunks of 128 (single iteration for uniform 128-node graphs) ----
    for (int r0 = 0; r0 < cnt; r0 += 128) {
        const int rows = min(128, cnt - r0);

        // Phase B: stage input rows (coalesced, conflict-free-enough writes)
        for (int jj = tid; jj < rows * (FIN / 4); jj += 256) {
            const int row = jj >> 6;
            const int col4 = jj & 63;
            *reinterpret_cast<float4*>(&in_s[row][col4 * 4]) =
                ip4[(size_t)(start + r0 + row) * (FIN / 4) + col4];
        }
        __syncthreads();  // covers m_s4 (first iter) + in_s

        // Phase C: GEMM. thread: r = tid>>2 (0..63) -> rows {r, r+64}, c4 = tid&3
        const int r = tid >> 2;
        const int c4 = tid & 3;
        float4 acc0 = make_float4(0.f, 0.f, 0.f, 0.f);
        float4 acc1 = make_float4(0.f, 0.f, 0.f, 0.f);

#pragma unroll 8
        for (int i4 = 0; i4 < FIN / 4; ++i4) {
            const float4 a0 = *reinterpret_cast<const float4*>(&in_s[r][i4 * 4]);
            const float4 a1 = *reinterpret_cast<const float4*>(&in_s[r + 64][i4 * 4]);
            const float4 m0 = m_s4[(i4 * 4 + 0) * 4 + c4];
            const float4 m1 = m_s4[(i4 * 4 + 1) * 4 + c4];
            const float4 m2 = m_s4[(i4 * 4 + 2) * 4 + c4];
            const float4 m3 = m_s4[(i4 * 4 + 3) * 4 + c4];

            acc0.x += a0.x * m0.x + a0.y * m1.x + a0.z * m2.x + a0.w * m3.x;
            acc0.y += a0.x * m0.y + a0.y * m1.y + a0.z * m2.y + a0.w * m3.y;
            acc0.z += a0.x * m0.z + a0.y * m1.z + a0.z * m2.z + a0.w * m3.z;
            acc0.w += a0.x * m0.w + a0.y * m1.w + a0.z * m2.w + a0.w * m3.w;

            acc1.x += a1.x * m0.x + a1.y * m1.x + a1.z * m2.x + a1.w * m3.x;
            acc1.y += a1.x * m0.y + a1.y * m1.y + a1.z * m2.y + a1.w * m3.y;
            acc1.z += a1.x * m0.z + a1.y * m1.z + a1.z * m2.z + a1.w * m3.z;
            acc1.w += a1.x * m0.w + a1.y * m1.w + a1.z * m2.w + a1.w * m3.w;
        }

        if (r < rows) {
            float4 t = acc0;
            t.x += bv.x; t.y += bv.y; t.z += bv.z; t.w += bv.w;
            out4[(size_t)(start + r0 + r) * (FOUT / 4) + co4 + c4] = t;
        }
        if (r + 64 < rows) {
            float4 t = acc1;
            t.x += bv.x; t.y += bv.y; t.z += bv.z; t.w += bv.w;
            out4[(size_t)(start + r0 + r + 64) * (FOUT / 4) + co4 + c4] = t;
        }
        __syncthreads();  // before next chunk overwrites in_s
    }
}

// ---------------------------------------------------------------------------
extern "C" void kernel_launch(void* const* d_in, const int* in_sizes, int n_in,
                              void* d_out, int out_size, void* d_ws, size_t ws_size,
                              hipStream_t stream) {
    const float* inputs = (const float*)d_in[0];   // (N, IN) f32
    const int* n_node = (const int*)d_in[1];       // (B,) i32
    const float* coeffs = (const float*)d_in[2];   // (B, E) f32
    const float* kern = (const float*)d_in[3];     // (E, IN, OUT) f32
    const float* bias = (const float*)d_in[4];     // (OUT,) f32
    float* outp = (float*)d_out;                   // (N, OUT) f32

    mole_onepass_kernel<<<NB * NSLICE, 256, 0, stream>>>(
        inputs, n_node, coeffs, kern, bias, outp);
}

// Round 5
// 17.746 us; speedup vs baseline: 3.4454x; 1.1852x over previous
//
#include <hip/hip_runtime.h>

#define NEXP 16
#define FIN 256
#define FOUT 256
#define NB 16
#define WCOL 16                 // output columns per block slice
#define NSLICE (FOUT / WCOL)    // 16 column slices per graph
#define MAT4 (FIN * FOUT / 4)   // 16384 float4 per (IN,OUT) matrix
#define PAD 2                   // in_s row pad (floats): 2-way banks = free

// ---------------------------------------------------------------------------
// Single fused kernel, no cross-block deps. 256 blocks x 1024 threads
// (16 waves = 4/SIMD; VGPR capped at 128 by launch_bounds).
// Block = (graph g, 16-col slice cs):
//   issue 8 staging loads -> mix 256x16 slice into LDS (1 pos/thread,
//   16 kern loads) -> drain staged input rows to LDS -> barrier ->
//   GEMM with 2-way K-split (waves 0-7: i<128, 8-15: i>=128) + 8 KB reduce.
// XCD swizzle: the 16 blocks sharing a kern column-slice land on one XCD.
// ---------------------------------------------------------------------------
__global__ __launch_bounds__(1024) void mole_onepass_kernel(
    const float* __restrict__ inp,     // (N, IN)
    const int* __restrict__ n_node,    // (B,)
    const float* __restrict__ coeffs,  // (B, E)
    const float* __restrict__ kern,    // (E, IN, OUT)
    const float* __restrict__ bias,    // (OUT,)
    float* __restrict__ out)           // (N, OUT)
{
    __shared__ float in_s[128][FIN + PAD];      // 132 KB
    __shared__ float4 m_s4[FIN * (WCOL / 4)];   // 16 KB, [i][c4] flat
    __shared__ float4 red_s[512];               // 8 KB K-split partials
    // total 156,672 B < 160 KiB

    const int tid = threadIdx.x;
    const int bid = blockIdx.x;

    // XCD-chunked decode: xcd = bid&7 owns column slices {2*xcd, 2*xcd+1}
    const int xcd = bid & 7;
    const int j = bid >> 3;               // 0..31
    const int cslice = 2 * xcd + (j & 1); // column slice 0..15
    const int g = j >> 1;                 // graph 0..15
    const int co4 = cslice * (WCOL / 4);  // float4 column offset

    // graph row range via prefix scan (ragged-safe, block-uniform scalar)
    int start = 0;
#pragma unroll
    for (int b = 0; b < NB; ++b) {
        const int nb = n_node[b];
        start += (b < g) ? nb : 0;
    }
    const int cnt = n_node[g];

    const float4* k4 = reinterpret_cast<const float4*>(kern);
    const float4* ip4 = reinterpret_cast<const float4*>(inp);
    float4* out4 = reinterpret_cast<float4*>(out);

    // mix mapping: 1 position per thread; m_s4 index == tid
    const int mi = tid >> 2;              // kern row i, 0..255
    const int mc4 = tid & 3;              // f4 col within slice
    const float4* kp = k4 + (size_t)mi * (FOUT / 4) + co4 + mc4;

    if (cnt == 128) {
        // ---- issue input-staging loads FIRST (latency hidden under mix) ----
        float4 st[8];
        const float4* ib = ip4 + (size_t)start * (FIN / 4);
#pragma unroll
        for (int k = 0; k < 8; ++k) st[k] = ib[tid + 1024 * k];

        // ---- mix: 16 expert loads + FMA, coeffs via uniform s_loads ----
        float4 macc = make_float4(0.f, 0.f, 0.f, 0.f);
#pragma unroll
        for (int e = 0; e < NEXP; ++e) {
            const float4 kv = kp[(size_t)e * MAT4];
            const float c = coeffs[g * NEXP + e];
            macc.x += c * kv.x;
            macc.y += c * kv.y;
            macc.z += c * kv.z;
            macc.w += c * kv.w;
        }
        m_s4[tid] = macc;

        // ---- drain staged rows to LDS (1 row per wave per k: conflict-free)
#pragma unroll
        for (int k = 0; k < 8; ++k) {
            const int jj = tid + 1024 * k;
            *reinterpret_cast<float4*>(&in_s[jj >> 6][(jj & 63) << 2]) = st[k];
        }
        __syncthreads();

        // ---- GEMM: thread = (row r, f4col c4, ksplit ks) ----
        const int rr = tid & 511;
        const int r = rr >> 2;            // 0..127
        const int c4 = rr & 3;
        const int ks = tid >> 9;          // 0 or 1
        const int i4base = ks << 5;
        float4 acc = make_float4(0.f, 0.f, 0.f, 0.f);
#pragma unroll 8
        for (int ii = 0; ii < 32; ++ii) {
            const int i4 = i4base + ii;
            const float4 a = *reinterpret_cast<const float4*>(&in_s[r][i4 << 2]);
            const float4 m0 = m_s4[((i4 << 2) + 0) * 4 + c4];
            const float4 m1 = m_s4[((i4 << 2) + 1) * 4 + c4];
            const float4 m2 = m_s4[((i4 << 2) + 2) * 4 + c4];
            const float4 m3 = m_s4[((i4 << 2) + 3) * 4 + c4];
            acc.x += a.x * m0.x + a.y * m1.x + a.z * m2.x + a.w * m3.x;
            acc.y += a.x * m0.y + a.y * m1.y + a.z * m2.y + a.w * m3.y;
            acc.z += a.x * m0.z + a.y * m1.z + a.z * m2.z + a.w * m3.z;
            acc.w += a.x * m0.w + a.y * m1.w + a.z * m2.w + a.w * m3.w;
        }
        if (ks) red_s[rr] = acc;
        __syncthreads();
        if (!ks) {
            const float4 p = red_s[rr];
            const float4 bv = reinterpret_cast<const float4*>(bias)[co4 + c4];
            acc.x += p.x + bv.x;
            acc.y += p.y + bv.y;
            acc.z += p.z + bv.z;
            acc.w += p.w + bv.w;
            out4[(size_t)(start + r) * (FOUT / 4) + co4 + c4] = acc;
        }
    } else {
        // ---- generic ragged fallback (never taken for uniform 128) ----
        float4 macc = make_float4(0.f, 0.f, 0.f, 0.f);
#pragma unroll
        for (int e = 0; e < NEXP; ++e) {
            const float4 kv = kp[(size_t)e * MAT4];
            const float c = coeffs[g * NEXP + e];
            macc.x += c * kv.x;
            macc.y += c * kv.y;
            macc.z += c * kv.z;
            macc.w += c * kv.w;
        }
        m_s4[tid] = macc;

        for (int r0 = 0; r0 < cnt; r0 += 128) {
            const int rows = min(128, cnt - r0);
            if (r0) __syncthreads();  // before overwriting in_s
            for (int jj = tid; jj < rows * (FIN / 4); jj += 1024) {
                *reinterpret_cast<float4*>(&in_s[jj >> 6][(jj & 63) << 2]) =
                    ip4[(size_t)(start + r0) * (FIN / 4) + jj];
            }
            __syncthreads();

            const int rr = tid & 511;
            const int r = rr >> 2;
            const int c4 = rr & 3;
            const int ks = tid >> 9;
            float4 acc = make_float4(0.f, 0.f, 0.f, 0.f);
            for (int ii = 0; ii < 32; ++ii) {
                const int i4 = (ks << 5) + ii;
                const float4 a = *reinterpret_cast<const float4*>(&in_s[r][i4 << 2]);
                const float4 m0 = m_s4[((i4 << 2) + 0) * 4 + c4];
                const float4 m1 = m_s4[((i4 << 2) + 1) * 4 + c4];
                const float4 m2 = m_s4[((i4 << 2) + 2) * 4 + c4];
                const float4 m3 = m_s4[((i4 << 2) + 3) * 4 + c4];
                acc.x += a.x * m0.x + a.y * m1.x + a.z * m2.x + a.w * m3.x;
                acc.y += a.x * m0.y + a.y * m1.y + a.z * m2.y + a.w * m3.y;
                acc.z += a.x * m0.z + a.y * m1.z + a.z * m2.z + a.w * m3.z;
                acc.w += a.x * m0.w + a.y * m1.w + a.z * m2.w + a.w * m3.w;
            }
            if (ks && r < rows) red_s[rr] = acc;
            __syncthreads();
            if (!ks && r < rows) {
                const float4 p = red_s[rr];
                const float4 bv = reinterpret_cast<const float4*>(bias)[co4 + c4];
                acc.x += p.x + bv.x;
                acc.y += p.y + bv.y;
                acc.z += p.z + bv.z;
                acc.w += p.w + bv.w;
                out4[(size_t)(start + r0 + r) * (FOUT / 4) + co4 + c4] = acc;
            }
        }
    }
}

// ---------------------------------------------------------------------------
extern "C" void kernel_launch(void* const* d_in, const int* in_sizes, int n_in,
                              void* d_out, int out_size, void* d_ws, size_t ws_size,
                              hipStream_t stream) {
    const float* inputs = (const float*)d_in[0];   // (N, IN) f32
    const int* n_node = (const int*)d_in[1];       // (B,) i32
    const float* coeffs = (const float*)d_in[2];   // (B, E) f32
    const float* kern = (const float*)d_in[3];     // (E, IN, OUT) f32
    const float* bias = (const float*)d_in[4];     // (OUT,) f32
    float* outp = (float*)d_out;                   // (N, OUT) f32

    mole_onepass_kernel<<<NB * NSLICE, 1024, 0, stream>>>(
        inputs, n_node, coeffs, kern, bias, outp);
}